// Round 13
// baseline (428.254 us; speedup 1.0000x reference)
//
#include <hip/hip_runtime.h>

// PSAMask collect: out[(nh*97+nw)*9409 + h*97 + w] = x[(nh-h+48)*97 + (nw-w+48)][h][w]
// (valid window, else 0). Pure shear permutation -> memory-bound.
//
// R13: persistent + pipelined + 2 blocks/CU (the cell R7/R9/R10 missed).
// 512 persistent blocks (LDS 77.8 KB -> 2/CU co-resident), each owns ~9-10
// (nh, h-pair) slots on ITS XCD (R8 pinning: nh -> XCD = blockIdx&7, chunks
// consecutive per nh). Single LDS buffer; pipeline via registers:
//   per slot: ds_read 37 vals -> VGPRs (masked) | lgkmcnt(0) | barrier |
//             DMA slot t+1 into LDS (38 loads)  | store slot t from regs (37)|
//             vmcnt(37) | barrier
// All per-wave vmem counts are UNIFORM (clamped lanes do benign duplicate
// work; LDS plane stride padded to 9728) -> vmcnt(37) provably retires the 38
// DMA loads while <=37 stores fly across the barrier. One cold drain total
// instead of ~9.3 per-generation drains (the ~45 us R8 overhead).
// Staging/LDS layout = R8 exactly (source-swizzled, conflict-free reads).

#define HW    97
#define PLANE 9409
#define HALF  48
#define NT    512
#define LNK   19        // DMA loads per plane per thread (ceil(9409/512))
#define PSTR  9728      // LDS floats per plane slot (19*512; pad 9409..9727)
#define SNK   37        // stores per thread (ceil(18818/512))
#define SOFF_LAST (96*PLANE + 193)        // clamped final element d=18817
#define SRD_LAST  (PSTR + 48*HW + 47)     // its LDS addr (hp=1,b=48,cw=47)

typedef const __attribute__((address_space(1))) void* gptr_t;
typedef __attribute__((address_space(3))) void* lptr_t;

__global__ __launch_bounds__(NT, 4)
void psamask_pers2(const float* __restrict__ x, float* __restrict__ out) {
    const unsigned tid = threadIdx.x;
    const unsigned xcd = blockIdx.x & 7u;
    const unsigned j   = blockIdx.x >> 3;          // 0..63 within XCD
    const unsigned cnt = (xcd == 0u) ? 13u : 12u;  // nh values owned by XCD
    const unsigned T   = cnt * 49u;                // slots on this XCD
    const unsigned s0  = (j * T) >> 6;
    const unsigned s1  = ((j + 1u) * T) >> 6;
    const int nslot = (int)(s1 - s0);              // 9 or 10

    __shared__ float lds[2 * PSTR];                // 77,824 B -> 2 blocks/CU

    const unsigned r0 = tid / HW;                  // 0..5
    const unsigned c0 = tid - r0 * HW;

    // stage one slot (2 planes): EXACTLY 2*LNK loads per thread, unconditional
    auto stage = [&](unsigned gs, unsigned cs) {
        int nh = (int)(8u * gs + xcd);
        int h0 = 2 * (int)cs; if (h0 > 95) h0 = 95;
        int a0 = nh - h0 + HALF;
        #pragma unroll
        for (int p = 0; p < 2; ++p) {
            int a = a0 - p;
            unsigned ac = (a < 0) ? 0u : ((a > 96) ? 96u : (unsigned)a); // garbage ok, masked later
            const float* xp = x + (size_t)(ac * HW) * PLANE + (unsigned)(h0 + p) * HW;
            unsigned b = r0, cw = c0;
            #pragma unroll
            for (int k = 0; k < LNK; ++k) {
                unsigned w = cw - b + ((cw < b) ? HW : 0u);     // (cw-b) mod 97
                unsigned soffk = (k == LNK - 1 && tid >= 193u)
                                   ? 0u : (b * PLANE + w);      // clamp tail lanes
                unsigned d0 = (unsigned)p * PSTR + (unsigned)k * NT + (tid & ~63u);
                __builtin_amdgcn_global_load_lds((gptr_t)(xp + soffk),
                                                 (lptr_t)&lds[d0], 4, 0, 0);
                b += 5; cw += 27;                   // 512 = 5*97 + 27
                if (cw >= HW) { cw -= HW; b += 1; }
            }
        }
    };

    // ---- prologue: stage slot s0, cold drain (once per kernel)
    unsigned g = s0 / 49u, cc = s0 - g * 49u;
    stage(g, cc);
    asm volatile("s_waitcnt vmcnt(0)" ::: "memory");
    __builtin_amdgcn_s_barrier();

    for (int i = 0; i < nslot; ++i) {
        const int nh = (int)(8u * g + xcd);
        int h0 = 2 * (int)cc; if (h0 > 95) h0 = 95;
        const int a0 = nh - h0 + HALF;
        const unsigned av0 = ((unsigned)a0       < HW) ? 1u : 0u;
        const unsigned av1 = ((unsigned)(a0 - 1) < HW) ? 1u : 0u;

        // ---- read phase: slot t LDS -> regs (masked); R8's verified walk
        float v[SNK];
        {
            unsigned q  = (tid >= 194u ? 1u : 0u) + (tid >= 388u ? 1u : 0u);
            unsigned e  = tid - q * 194u;
            unsigned cw = q + HALF;                 // q<=2 -> cw<97
            #pragma unroll
            for (int k = 0; k < SNK; ++k) {
                unsigned hp = (e >= 97u) ? 1u : 0u;
                unsigned w  = e - hp * 97u;
                int b = (int)q - (int)w + HALF;     // nw - w + 48
                bool vb = ((unsigned)b < HW);
                unsigned bc = vb ? (unsigned)b : 0u;
                unsigned srd = hp * PSTR + bc * HW + cw;
                unsigned av  = hp ? av1 : av0;
                if (k == SNK - 1) {                 // clamped lanes: fixed element 18817
                    if (tid >= 386u) { srd = SRD_LAST; av = av1; vb = true; }
                }
                float val = lds[srd];
                v[k] = (vb && av) ? val : 0.0f;
                e += 124u; q += 2u; cw += 2u;
                if (e >= 194u) { e -= 194u; q += 1u; cw += 1u; }
                if (cw >= 97u) cw -= 97u;
            }
        }
        asm volatile("s_waitcnt lgkmcnt(0)" ::: "memory");
        __builtin_amdgcn_sched_barrier(0);
        __builtin_amdgcn_s_barrier();               // all waves' reads done

        // ---- prefetch slot t+1 into the same LDS (issue-only; block-uniform)
        unsigned gn = g, cn = cc + 1u;
        if (cn == 49u) { cn = 0u; gn += 1u; }
        if (i + 1 < nslot) stage(gn, cn);           // 38 loads

        // ---- store slot t from regs: 37 stores, unconditional
        {
            float* op = out + (size_t)((unsigned)nh * HW) * PLANE + (unsigned)h0 * HW;
            unsigned q   = (tid >= 194u ? 1u : 0u) + (tid >= 388u ? 1u : 0u);
            unsigned e   = tid - q * 194u;
            unsigned off = q * PLANE + e;
            #pragma unroll
            for (int k = 0; k < SNK; ++k) {
                unsigned offk = off;
                if (k == SNK - 1 && tid >= 386u) offk = SOFF_LAST; // dup store, same value
                op[offk] = v[k];
                e += 124u; q += 2u; off += 2u * PLANE + 124u;
                if (e >= 194u) { e -= 194u; q += 1u; off += PLANE - 194u; }
            }
        }
        // retire this slot's 38 loads; leave <=37 stores in flight across barrier
        asm volatile("s_waitcnt vmcnt(37)" ::: "memory");
        __builtin_amdgcn_s_barrier();
        g = gn; cc = cn;
    }
}

extern "C" void kernel_launch(void* const* d_in, const int* in_sizes, int n_in,
                              void* d_out, int out_size, void* d_ws, size_t ws_size,
                              hipStream_t stream) {
    const float* x = (const float*)d_in[0];
    float* out = (float*)d_out;
    psamask_pers2<<<dim3(512), NT, 0, stream>>>(x, out);
}

// Round 14
// 157.311 us; speedup vs baseline: 2.7223x; 2.7223x over previous
//
#include <hip/hip_runtime.h>

// PSAMask collect: out[(nh*97+nw)*9409 + h*97 + w] = x[(nh-h+48)*97 + (nw-w+48)][h][w]
// (valid window, else 0). Pure permutation -> memory-bound.
//
// FINAL (= R8, the measured optimum of 10 structural variants at 158 us):
// h-pair blocks, 2 planes in LDS (75 KB -> 2 blocks/CU), 776 B contiguous
// write runs per output channel, XCD-pinned write windows (nh -> XCD = l&7,
// all 49 h-chunks of one nh consecutive on that XCD), full vmcnt(0) drain
// (counted-vmcnt races on divergent tails; persistent variants break L2/L3
// locality: R13 FETCH 171->741 MB).
// LDS source-swizzled per plane: lds[p][b*97 + (w+b)%97] = x[b][w] ->
// diagonal read (b = nw-w+48, col (nw+48)%97) has lane bank delta -1.
// Structural floor argument: traffic is ideal (171+419 MB measured); write
// granule is capped at 2 rows x 388 B by LDS-capacity x 2-block-occupancy
// (4-row variants all >= 171 us); 776 B scatter at 37.6 KB stride runs DRAM
// at ~55-60% stream efficiency -> ~158 us.

#define HW    97
#define PLANE 9409      // 97*97
#define HALF  48
#define NT    512
#define NITER 19        // ceil(PLANE/NT); 9409 = 18*512 + 193
#define RUN   194       // 2*97 floats per channel run
#define TOT2  18818     // 2*PLANE
#define WITER 37        // ceil(TOT2/NT); 18818 = 36*512 + 386

typedef const __attribute__((address_space(1))) void* gptr_t;
typedef __attribute__((address_space(3))) void* lptr_t;

__global__ __launch_bounds__(NT)
void psamask_collect_kernel(const float* __restrict__ x, float* __restrict__ out) {
    // ---- XCD-pinned decode: k = XCD digit -> nh = 8*g + k, c sweeps within nh
    const unsigned l = blockIdx.x;
    const unsigned k8 = l & 7u;
    const unsigned m  = l >> 3;          // 0..636
    const unsigned g  = m / 49u;
    const unsigned c  = m - g * 49u;     // 0..48 (h-pair chunk)
    const int nh = (int)(g * 8u + k8);
    if (nh > 96) return;                 // padded blocks

    const int h0 = 2 * (int)c;
    const int TH = (h0 == 96) ? 1 : 2;
    const unsigned tid = threadIdx.x;

    const unsigned r0 = tid / HW;        // 0..5
    const unsigned c0 = tid - r0 * HW;

    __shared__ float lds[2 * PLANE];     // 75,272 B -> 2 blocks/CU

    const int a0 = nh - h0 + HALF;
    const bool av0 = ((unsigned)a0 < HW);
    const bool av1 = (TH == 2) && ((unsigned)(a0 - 1) < HW);

    // ---- stage up to 2 planes (async DMA, source-swizzled), single drain
    #pragma unroll
    for (int p = 0; p < 2; ++p) {
        const bool av = p ? av1 : av0;
        if (!av) continue;
        const float* __restrict__ xp =
            x + (size_t)((unsigned)(a0 - p) * HW) * PLANE + (unsigned)(h0 + p) * HW;
        unsigned b = r0, cw = c0;        // flat dest d = b*97 + cw
        #pragma unroll
        for (int kk = 0; kk < NITER; ++kk) {
            unsigned d = tid + (unsigned)kk * NT;
            if (d < PLANE) {
                unsigned w = cw - b + ((cw < b) ? HW : 0u);       // (cw-b) mod 97
                const float* gsrc = xp + b * PLANE + w;           // per-lane source
                unsigned d0 = (unsigned)p * PLANE + (unsigned)kk * NT + (tid & ~63u);
                __builtin_amdgcn_global_load_lds((gptr_t)gsrc, (lptr_t)&lds[d0], 4, 0, 0);
            }
            b += 5; cw += 27;            // 512 = 5*97 + 27
            if (cw >= HW) { cw -= HW; b += 1; }
        }
    }
    asm volatile("s_waitcnt vmcnt(0)" ::: "memory");
    __syncthreads();

    float* __restrict__ outp =
        out + (size_t)((unsigned)nh * HW) * PLANE + (unsigned)h0 * HW;

    if (TH == 2) {
        // elements p = q*194 + e over all 97 channels' contiguous 2-row runs
        unsigned q  = (tid >= RUN ? 1u : 0u) + (tid >= 2u * RUN ? 1u : 0u);
        unsigned e  = tid - q * RUN;
        unsigned cw = q + HALF;                          // (q+48), q0<=2 so <97
        unsigned off = q * PLANE + e;
        #pragma unroll
        for (int kk = 0; kk < WITER; ++kk) {
            unsigned d = tid + (unsigned)kk * NT;
            if (d < TOT2) {
                unsigned hp = (e >= HW) ? 1u : 0u;       // which plane/row
                unsigned w  = e - hp * HW;
                int b = (int)q - (int)w + HALF;          // nw - w + 48
                bool vb = ((unsigned)b < HW);
                unsigned bc = vb ? (unsigned)b : 0u;
                float v = lds[hp * PLANE + bc * HW + cw];
                bool av = hp ? av1 : av0;
                outp[off] = (vb && av) ? v : 0.0f;
            }
            // p += 512 = 2*194 + 124
            e += 124u; q += 2u; cw += 2u; off += 2u * PLANE + 124u;
            if (e >= RUN) { e -= RUN; q += 1u; cw += 1u; off += PLANE - RUN; }
            if (cw >= HW) cw -= HW;
        }
    } else {
        // last chunk: single row h = 96
        unsigned w   = c0;
        int      b   = (int)r0 - (int)c0 + HALF;
        unsigned cw  = r0 + HALF; if (cw >= HW) cw -= HW;
        unsigned off = r0 * PLANE + c0;
        #pragma unroll
        for (int kk = 0; kk < NITER; ++kk) {
            unsigned d = tid + (unsigned)kk * NT;
            if (d < PLANE) {
                bool vb = ((unsigned)b < HW);
                unsigned bc = vb ? (unsigned)b : 0u;
                float v = lds[bc * HW + cw];
                outp[off] = (vb && av0) ? v : 0.0f;
            }
            w += 27;
            bool wrap = (w >= HW);
            if (wrap) w -= HW;
            b  += wrap ? 76 : -22;
            cw += wrap ? 6u : 5u;
            if (cw >= HW) cw -= HW;
            off += wrap ? (6u * PLANE - 70u) : (5u * PLANE + 27u);
        }
    }
}

extern "C" void kernel_launch(void* const* d_in, const int* in_sizes, int n_in,
                              void* d_out, int out_size, void* d_ws, size_t ws_size,
                              hipStream_t stream) {
    const float* x = (const float*)d_in[0];
    float* out = (float*)d_out;
    // 8 XCD digits x 637 (= 13*49) inner slots; nh>96 blocks early-exit (+7% pad)
    psamask_collect_kernel<<<dim3(5096), NT, 0, stream>>>(x, out);
}